// Round 9
// baseline (57446.021 us; speedup 1.0000x reference)
//
#include <hip/hip_runtime.h>
#include <hip/hip_fp16.h>
#include <cstdint>
#include <cstddef>

#define N_E 2048
#define N_I 512
#define N_TOT 2560
#define BATCH 64
#define TSTEPS 512
#define INDIM 128
#define CAP (1u << 20)   // nz capacity (expected ~330K)

// ------------------------------------------------------------------
// CSC build: counts -> scan -> fill.
// Synapse packed u32: (f16_bits(w) << 16) | post_index   (4 B/synapse)
// colinfo packed u32: (col_begin << 10) | col_len
// ------------------------------------------------------------------
__global__ void count_kernel(const float* __restrict__ Wee, const float* __restrict__ Wie,
                             const float* __restrict__ Wei, const float* __restrict__ Wii,
                             unsigned* __restrict__ cnt)
{
    const long EE = (long)N_E * N_E;
    const long IE = (long)N_I * N_E;
    const long EI = (long)N_E * N_I;
    const long II = (long)N_I * N_I;
    long idx = (long)blockIdx.x * 256 + threadIdx.x;
    long total = EE + IE + EI + II;
    if (idx >= total) return;
    float v; int col;
    if (idx < EE) {
        v = Wee[idx]; col = (int)(idx & (N_E - 1));
    } else if (idx < EE + IE) {
        long j = idx - EE; v = Wie[j]; col = (int)(j & (N_E - 1));
    } else if (idx < EE + IE + EI) {
        long j = idx - EE - IE; v = Wei[j]; col = N_E + (int)(j & (N_I - 1));
    } else {
        long j = idx - EE - IE - EI; v = Wii[j]; col = N_E + (int)(j & (N_I - 1));
    }
    if (v > 0.0f) atomicAdd(&cnt[col], 1u);
}

__global__ void scan_kernel(const unsigned* __restrict__ cnt,
                            unsigned* __restrict__ colinfo, unsigned* __restrict__ cursor)
{
    __shared__ unsigned sums[256];
    int t = threadIdx.x;
    int base = t * 10;                 // 2560 = 256 * 10
    unsigned loc[10];
    unsigned s = 0;
    for (int i = 0; i < 10; ++i) { loc[i] = s; s += cnt[base + i]; }
    sums[t] = s;
    __syncthreads();
    if (t == 0) {
        unsigned a = 0;
        for (int i = 0; i < 256; ++i) { unsigned v = sums[i]; sums[i] = a; a += v; }
    }
    __syncthreads();
    unsigned offt = sums[t];
    for (int i = 0; i < 10; ++i) {
        unsigned beg = offt + loc[i];
        if (beg > CAP) beg = CAP;
        unsigned len = cnt[base + i];
        if (len > 1023u) len = 1023u;
        colinfo[base + i] = (beg << 10) | len;
        cursor[base + i] = beg;
    }
}

__global__ void fill_kernel(const float* __restrict__ Wee, const float* __restrict__ Wie,
                            const float* __restrict__ Wei, const float* __restrict__ Wii,
                            unsigned* __restrict__ cursor,
                            unsigned* __restrict__ nzd)
{
    const long EE = (long)N_E * N_E;
    const long IE = (long)N_I * N_E;
    const long EI = (long)N_E * N_I;
    const long II = (long)N_I * N_I;
    long idx = (long)blockIdx.x * 256 + threadIdx.x;
    long total = EE + IE + EI + II;
    if (idx >= total) return;
    float v; int col; int post; bool neg;
    if (idx < EE) {
        int r = (int)(idx >> 11), c = (int)(idx & (N_E - 1));
        v = Wee[idx]; post = r; col = c; neg = false;
    } else if (idx < EE + IE) {
        long j = idx - EE;
        int r = (int)(j >> 11), c = (int)(j & (N_E - 1));
        v = Wie[j]; post = N_E + r; col = c; neg = false;
    } else if (idx < EE + IE + EI) {
        long j = idx - EE - IE;
        int r = (int)(j >> 9), c = (int)(j & (N_I - 1));
        v = Wei[j]; post = r; col = N_E + c; neg = true;
    } else {
        long j = idx - EE - IE - EI;
        int r = (int)(j >> 9), c = (int)(j & (N_I - 1));
        v = Wii[j]; post = N_E + r; col = N_E + c; neg = true;
    }
    if (v > 0.0f) {
        unsigned pos = atomicAdd(&cursor[col], 1u);
        if (pos < CAP) {
            float w = neg ? -v : v;
            unsigned short h = __half_as_ushort(__float2half(w));
            nzd[pos] = ((unsigned)h << 16) | (unsigned)post;
        }
    }
}

// ------------------------------------------------------------------
// Input projection GEMM (unchanged)
// ------------------------------------------------------------------
#define PBM 128
#define PBN 64
#define PBK 32
__global__ __launch_bounds__(256) void proj_kernel(
    const float* __restrict__ x, const float* __restrict__ We, const float* __restrict__ Wi,
    float* __restrict__ out, int t0)
{
    __shared__ __align__(16) float As[PBK][132];
    __shared__ __align__(16) float Bs[PBK][68];
    int tid = threadIdx.x;
    int bx = blockIdx.x, by = blockIdx.y;
    int tx = tid & 15, ty = tid >> 4;
    float acc[8][4];
#pragma unroll
    for (int i = 0; i < 8; ++i)
#pragma unroll
        for (int j = 0; j < 4; ++j) acc[i][j] = 0.0f;

    for (int kb = 0; kb < INDIM; kb += PBK) {
#pragma unroll
        for (int it = 0; it < 4; ++it) {
            int idx = it * 256 + tid;
            int kq = idx & 7, ml = idx >> 3;
            int m = by * PBM + ml;
            int b = m & 63, tl = m >> 6;
            const float* arow = x + ((size_t)b * TSTEPS + (size_t)(t0 + tl)) * INDIM;
            float4 v = *(const float4*)(arow + kb + kq * 4);
            As[kq * 4 + 0][ml] = v.x; As[kq * 4 + 1][ml] = v.y;
            As[kq * 4 + 2][ml] = v.z; As[kq * 4 + 3][ml] = v.w;
        }
#pragma unroll
        for (int it = 0; it < 2; ++it) {
            int idx = it * 256 + tid;
            int kq = idx & 7, nl = idx >> 3;
            int n = bx * PBN + nl;
            const float* brow = (n < N_E) ? (We + (size_t)n * INDIM)
                                          : (Wi + (size_t)(n - N_E) * INDIM);
            float4 v = *(const float4*)(brow + kb + kq * 4);
            Bs[kq * 4 + 0][nl] = v.x; Bs[kq * 4 + 1][nl] = v.y;
            Bs[kq * 4 + 2][nl] = v.z; Bs[kq * 4 + 3][nl] = v.w;
        }
        __syncthreads();
#pragma unroll
        for (int k = 0; k < PBK; ++k) {
            float4 a0 = *(const float4*)&As[k][ty * 8];
            float4 a1 = *(const float4*)&As[k][ty * 8 + 4];
            float4 b0 = *(const float4*)&Bs[k][tx * 4];
            float a[8] = {a0.x, a0.y, a0.z, a0.w, a1.x, a1.y, a1.z, a1.w};
            float bb[4] = {b0.x, b0.y, b0.z, b0.w};
#pragma unroll
            for (int i = 0; i < 8; ++i)
#pragma unroll
                for (int j = 0; j < 4; ++j)
                    acc[i][j] = fmaf(a[i], bb[j], acc[i][j]);
        }
        __syncthreads();
    }
#pragma unroll
    for (int i = 0; i < 8; ++i) {
        int m = by * PBM + ty * 8 + i;
        float4 o = make_float4(acc[i][0], acc[i][1], acc[i][2], acc[i][3]);
        *(float4*)(out + (size_t)m * N_TOT + bx * PBN + tx * 4) = o;
    }
}

__device__ __forceinline__ float inline_proj(const float* __restrict__ x,
                                             const float* __restrict__ We_in,
                                             const float* __restrict__ Wi_in,
                                             int b, int t, int n)
{
    const float* xr = x + ((size_t)b * TSTEPS + (size_t)t) * INDIM;
    const float* wr = (n < N_E) ? (We_in + (size_t)n * INDIM)
                                : (Wi_in + (size_t)(n - N_E) * INDIM);
    float a = 0.f;
#pragma unroll
    for (int k = 0; k < INDIM; k += 4) {
        float4 w = *(const float4*)(wr + k);
        float4 xv = *(const float4*)(xr + k);
        a = fmaf(w.x, xv.x, a);
        a = fmaf(w.y, xv.y, a);
        a = fmaf(w.z, xv.z, a);
        a = fmaf(w.w, xv.w, a);
    }
    return a;
}

// ------------------------------------------------------------------
// Real sim kernel — identical to round 8 (produces the output).
// ------------------------------------------------------------------
__global__ __launch_bounds__(1024) void sim_kernel(
    const float* __restrict__ i_inp,
    const float* __restrict__ x, const float* __restrict__ We_in, const float* __restrict__ Wi_in,
    const unsigned* __restrict__ colinfo, const unsigned* __restrict__ nzd,
    float* __restrict__ gv_e, float* __restrict__ gi_e,
    float* __restrict__ gv_i, float* __restrict__ gi_i,
    unsigned* __restrict__ g_cnt, int* __restrict__ g_list, int* __restrict__ g_nspk,
    int t0, int tc, int first)
{
    __shared__ float I_acc[2][N_TOT];
    __shared__ unsigned ci_lds[N_TOT];
    __shared__ int list_s[2][N_TOT];
    __shared__ int nspk_s[2];

    int b = blockIdx.x, tid = threadIdx.x;
    int lane = tid & 63, wid = tid >> 6;

    for (int n = tid; n < N_TOT; n += 1024) ci_lds[n] = colinfo[n];

    float v0, v1, v2, c0, c1, c2;
    unsigned cnt0, cnt1;
    if (first) {
        v0 = v1 = v2 = 0.f; c0 = c1 = c2 = 0.f; cnt0 = cnt1 = 0u;
        if (tid == 0) nspk_s[0] = 0;
    } else {
        v0 = gv_e[(size_t)b * N_E + tid];
        c0 = gi_e[(size_t)b * N_E + tid];
        cnt0 = g_cnt[(size_t)b * N_E + tid];
        v1 = gv_e[(size_t)b * N_E + tid + 1024];
        c1 = gi_e[(size_t)b * N_E + tid + 1024];
        cnt1 = g_cnt[(size_t)b * N_E + tid + 1024];
        if (tid < N_I) { v2 = gv_i[(size_t)b * N_I + tid]; c2 = gi_i[(size_t)b * N_I + tid]; }
        else { v2 = 0.f; c2 = 0.f; }
        if (tid == 0) nspk_s[0] = g_nspk[b];
        __syncthreads();
        for (int s = tid; s < nspk_s[0]; s += 1024) list_s[0][s] = g_list[(size_t)b * N_TOT + s];
    }
    if (i_inp) {
        if (tid < 640) {
            float4 vv = *(const float4*)(i_inp + (size_t)b * N_TOT + tid * 4);
            *(float4*)&I_acc[0][tid * 4] = vv;
        }
    } else {
        for (int n = tid; n < N_TOT; n += 1024)
            I_acc[0][n] = inline_proj(x, We_in, Wi_in, b, t0, n);
    }
    __syncthreads();

    for (int tl = 0; tl < tc; ++tl) {
        int cur = tl & 1, nxt = cur ^ 1;
        if (tid == 0) nspk_s[nxt] = 0;

        if (tl + 1 < tc) {
            if (i_inp) {
                if (tid < 640) {
                    float4 vv = *(const float4*)(i_inp +
                        ((size_t)(tl + 1) * BATCH + b) * N_TOT + tid * 4);
                    *(float4*)&I_acc[nxt][tid * 4] = vv;
                }
            } else {
                for (int n = tid; n < N_TOT; n += 1024)
                    I_acc[nxt][n] = inline_proj(x, We_in, Wi_in, b, t0 + tl + 1, n);
            }
        }

        int ns = nspk_s[cur];
        int Mw = (ns > wid) ? ((ns - wid + 15) >> 4) : 0;
        for (int m0 = 0; m0 < Mw; m0 += 64) {
            int m = m0 + lane;
            unsigned ci = 0u;
            if (m < Mw) ci = ci_lds[list_s[cur][wid + (m << 4)]];
            int nv = Mw - m0; if (nv > 64) nv = 64;
            for (int k = 0; k < nv; ++k) {
                unsigned cik = (unsigned)__shfl((int)ci, k);
                int len = (int)(cik & 1023u);
                unsigned beg = cik >> 10;
                unsigned e0 = (lane < len) ? nzd[beg + lane] : 0u;
                unsigned e1 = (lane + 64 < len) ? nzd[beg + lane + 64] : 0u;
                unsigned e2 = (lane + 128 < len) ? nzd[beg + lane + 128] : 0u;
                if (lane < len)
                    atomicAdd(&I_acc[cur][e0 & 0xFFFFu],
                              __half2float(__ushort_as_half((unsigned short)(e0 >> 16))));
                if (lane + 64 < len)
                    atomicAdd(&I_acc[cur][e1 & 0xFFFFu],
                              __half2float(__ushort_as_half((unsigned short)(e1 >> 16))));
                if (lane + 128 < len)
                    atomicAdd(&I_acc[cur][e2 & 0xFFFFu],
                              __half2float(__ushort_as_half((unsigned short)(e2 >> 16))));
                for (int p = lane + 192; p < len; p += 64) {
                    unsigned ev = nzd[beg + p];
                    atomicAdd(&I_acc[cur][ev & 0xFFFFu],
                              __half2float(__ushort_as_half((unsigned short)(ev >> 16))));
                }
            }
        }
        __syncthreads();

        {
            float I0 = I_acc[cur][tid];
            float I1 = I_acc[cur][tid + 1024];
            float I2 = (tid < N_I) ? I_acc[cur][tid + 2048] : 0.f;

            float vd0 = v0 + 0.05f * (c0 - v0);
            bool z0 = vd0 > 1.0f;
            v0 = z0 ? 0.f : vd0;  c0 = 0.8f * c0 + I0;  if (z0) cnt0++;

            float vd1 = v1 + 0.05f * (c1 - v1);
            bool z1 = vd1 > 1.0f;
            v1 = z1 ? 0.f : vd1;  c1 = 0.8f * c1 + I1;  if (z1) cnt1++;

            float vd2 = v2 + 0.1f * (c2 - v2);
            bool z2 = (tid < N_I) && (vd2 > 1.0f);
            v2 = z2 ? 0.f : vd2;  c2 = 0.8f * c2 + I2;

            unsigned long long mk0 = __ballot(z0);
            unsigned long long mk1 = __ballot(z1);
            unsigned long long mk2 = __ballot(z2);
            int wc0 = __popcll(mk0), wc1 = __popcll(mk1), wc2 = __popcll(mk2);
            int tot = wc0 + wc1 + wc2;
            if (tot) {
                int base = 0;
                if (lane == 0) base = atomicAdd(&nspk_s[nxt], tot);
                base = __shfl(base, 0);
                unsigned long long pre = (1ull << lane) - 1ull;
                if (z0) list_s[nxt][base + __popcll(mk0 & pre)] = tid;
                if (z1) list_s[nxt][base + wc0 + __popcll(mk1 & pre)] = tid + 1024;
                if (z2) list_s[nxt][base + wc0 + wc1 + __popcll(mk2 & pre)] = tid + 2048;
            }
        }
        __syncthreads();
    }

    gv_e[(size_t)b * N_E + tid] = v0;
    gi_e[(size_t)b * N_E + tid] = c0;
    g_cnt[(size_t)b * N_E + tid] = cnt0;
    gv_e[(size_t)b * N_E + tid + 1024] = v1;
    gi_e[(size_t)b * N_E + tid + 1024] = c1;
    g_cnt[(size_t)b * N_E + tid + 1024] = cnt1;
    if (tid < N_I) {
        gv_i[(size_t)b * N_I + tid] = v2;
        gi_i[(size_t)b * N_I + tid] = c2;
    }
    int fin = tc & 1;
    if (tid == 0) g_nspk[b] = nspk_s[fin];
    for (int s = tid; s < nspk_s[fin]; s += 1024) g_list[(size_t)b * N_TOT + s] = list_s[fin][s];
}

// ------------------------------------------------------------------
// ABLATION PROBE: identical structure, but the spike list is FORCED
// to a fixed count of hash-generated columns each step. Writes dummy
// state only. FORCED=0 gives the intercept (barriers+input+LIF);
// slope vs FORCED gives ns/spike; inversion gives the real ns.
// ------------------------------------------------------------------
template<int FORCED>
__global__ __launch_bounds__(1024) void sim_probe(
    const float* __restrict__ i_inp,
    const unsigned* __restrict__ colinfo, const unsigned* __restrict__ nzd,
    float* __restrict__ dv, float* __restrict__ di, unsigned* __restrict__ dcnt,
    int tc)
{
    __shared__ float I_acc[2][N_TOT];
    __shared__ unsigned ci_lds[N_TOT];
    __shared__ int list_s[2][N_TOT];
    __shared__ int nspk_s[2];

    int b = blockIdx.x, tid = threadIdx.x;
    int lane = tid & 63, wid = tid >> 6;

    for (int n = tid; n < N_TOT; n += 1024) ci_lds[n] = colinfo[n];

    float v0 = 0.f, v1 = 0.f, v2 = 0.f, c0 = 0.f, c1 = 0.f, c2 = 0.f;
    unsigned cnt0 = 0u, cnt1 = 0u;
    if (tid == 0) { nspk_s[0] = FORCED; }
    for (int s = tid; s < FORCED; s += 1024)
        list_s[0][s] = (int)(((unsigned)s * 2017u) % (unsigned)N_TOT);
    if (tid < 640) {
        float4 vv = *(const float4*)(i_inp + (size_t)b * N_TOT + tid * 4);
        *(float4*)&I_acc[0][tid * 4] = vv;
    }
    __syncthreads();

    for (int tl = 0; tl < tc; ++tl) {
        int cur = tl & 1, nxt = cur ^ 1;
        if (tid == 0) nspk_s[nxt] = FORCED;

        if (tl + 1 < tc) {
            if (tid < 640) {
                float4 vv = *(const float4*)(i_inp +
                    ((size_t)(tl + 1) * BATCH + b) * N_TOT + tid * 4);
                *(float4*)&I_acc[nxt][tid * 4] = vv;
            }
        }

        int ns = nspk_s[cur];
        int Mw = (ns > wid) ? ((ns - wid + 15) >> 4) : 0;
        for (int m0 = 0; m0 < Mw; m0 += 64) {
            int m = m0 + lane;
            unsigned ci = 0u;
            if (m < Mw) ci = ci_lds[list_s[cur][wid + (m << 4)]];
            int nv = Mw - m0; if (nv > 64) nv = 64;
            for (int k = 0; k < nv; ++k) {
                unsigned cik = (unsigned)__shfl((int)ci, k);
                int len = (int)(cik & 1023u);
                unsigned beg = cik >> 10;
                unsigned e0 = (lane < len) ? nzd[beg + lane] : 0u;
                unsigned e1 = (lane + 64 < len) ? nzd[beg + lane + 64] : 0u;
                unsigned e2 = (lane + 128 < len) ? nzd[beg + lane + 128] : 0u;
                if (lane < len)
                    atomicAdd(&I_acc[cur][e0 & 0xFFFFu],
                              __half2float(__ushort_as_half((unsigned short)(e0 >> 16))));
                if (lane + 64 < len)
                    atomicAdd(&I_acc[cur][e1 & 0xFFFFu],
                              __half2float(__ushort_as_half((unsigned short)(e1 >> 16))));
                if (lane + 128 < len)
                    atomicAdd(&I_acc[cur][e2 & 0xFFFFu],
                              __half2float(__ushort_as_half((unsigned short)(e2 >> 16))));
                for (int p = lane + 192; p < len; p += 64) {
                    unsigned ev = nzd[beg + p];
                    atomicAdd(&I_acc[cur][ev & 0xFFFFu],
                              __half2float(__ushort_as_half((unsigned short)(ev >> 16))));
                }
            }
        }
        __syncthreads();

        {
            float I0 = I_acc[cur][tid];
            float I1 = I_acc[cur][tid + 1024];
            float I2 = (tid < N_I) ? I_acc[cur][tid + 2048] : 0.f;

            float vd0 = v0 + 0.05f * (c0 - v0);
            bool z0 = vd0 > 1.0f;
            v0 = z0 ? 0.f : vd0;  c0 = 0.8f * c0 + I0;  if (z0) cnt0++;

            float vd1 = v1 + 0.05f * (c1 - v1);
            bool z1 = vd1 > 1.0f;
            v1 = z1 ? 0.f : vd1;  c1 = 0.8f * c1 + I1;  if (z1) cnt1++;

            float vd2 = v2 + 0.1f * (c2 - v2);
            bool z2 = (tid < N_I) && (vd2 > 1.0f);
            v2 = z2 ? 0.f : vd2;  c2 = 0.8f * c2 + I2;

            // forced list for next step (replaces the ballot append)
            for (int s = tid; s < FORCED; s += 1024)
                list_s[nxt][s] = (int)((((unsigned)s * 2017u) + (unsigned)(tl + 1) * 911u)
                                       % (unsigned)N_TOT);
        }
        __syncthreads();
    }

    dv[(size_t)b * N_E + tid] = v0 + v2;
    di[(size_t)b * N_E + tid] = c0 + c2;
    dcnt[(size_t)b * N_E + tid] = cnt0;
    dv[(size_t)b * N_E + ((tid + 1024) & (N_E - 1))] += v1;
    di[(size_t)b * N_E + ((tid + 1024) & (N_E - 1))] += c1;
    dcnt[(size_t)b * N_E + ((tid + 1024) & (N_E - 1))] += cnt1;
}

// ------------------------------------------------------------------
// Readout
// ------------------------------------------------------------------
__global__ __launch_bounds__(256) void readout_kernel(
    const unsigned* __restrict__ g_cnt,
    const float* __restrict__ rw, const float* __restrict__ rb, float* __restrict__ out)
{
    int b = blockIdx.x, tid = threadIdx.x;
    float a0 = 0.f, a1 = 0.f, a2 = 0.f;
    for (int n = tid; n < N_E; n += 256) {
        float c = (float)g_cnt[(size_t)b * N_E + n];
        a0 = fmaf(c, rw[n], a0);
        a1 = fmaf(c, rw[N_E + n], a1);
        a2 = fmaf(c, rw[2 * N_E + n], a2);
    }
#pragma unroll
    for (int off = 32; off > 0; off >>= 1) {
        a0 += __shfl_down(a0, off);
        a1 += __shfl_down(a1, off);
        a2 += __shfl_down(a2, off);
    }
    __shared__ float part[3][4];
    int wid = tid >> 6, lane = tid & 63;
    if (lane == 0) { part[0][wid] = a0; part[1][wid] = a1; part[2][wid] = a2; }
    __syncthreads();
    if (tid == 0) {
        float s0 = part[0][0] + part[0][1] + part[0][2] + part[0][3];
        float s1 = part[1][0] + part[1][1] + part[1][2] + part[1][3];
        float s2 = part[2][0] + part[2][1] + part[2][2] + part[2][3];
        const float inv = 1.0f / 512.0f;
        out[b * 3 + 0] = fmaf(s0, inv, rb[0]);
        out[b * 3 + 1] = fmaf(s1, inv, rb[1]);
        out[b * 3 + 2] = fmaf(s2, inv, rb[2]);
    }
}

// ------------------------------------------------------------------
extern "C" void kernel_launch(void* const* d_in, const int* in_sizes, int n_in,
                              void* d_out, int out_size, void* d_ws, size_t ws_size,
                              hipStream_t stream)
{
    const float* x     = (const float*)d_in[0];
    const float* Wee   = (const float*)d_in[1];
    const float* Wie   = (const float*)d_in[2];
    const float* Wei   = (const float*)d_in[3];
    const float* Wii   = (const float*)d_in[4];
    const float* We_in = (const float*)d_in[5];
    const float* Wi_in = (const float*)d_in[6];
    const float* rw    = (const float*)d_in[7];
    const float* rb    = (const float*)d_in[8];
    float* out = (float*)d_out;
    char* ws = (char*)d_ws;

    size_t off = 0;
    auto alloc = [&](size_t bytes) {
        size_t o = off;
        off = (off + bytes + 255) & ~(size_t)255;
        return o;
    };
    size_t o_cnt     = alloc((size_t)N_TOT * 4);
    size_t o_colinfo = alloc((size_t)N_TOT * 4);
    size_t o_cursor  = alloc((size_t)N_TOT * 4);
    size_t o_nzd     = alloc((size_t)CAP * 4);
    size_t o_ve      = alloc((size_t)BATCH * N_E * 4);
    size_t o_ie      = alloc((size_t)BATCH * N_E * 4);
    size_t o_vi      = alloc((size_t)BATCH * N_I * 4);
    size_t o_ii      = alloc((size_t)BATCH * N_I * 4);
    size_t o_gcnt    = alloc((size_t)BATCH * N_E * 4);
    size_t o_glist   = alloc((size_t)BATCH * N_TOT * 4);
    size_t o_gnspk   = alloc((size_t)BATCH * 4);
    size_t o_dv      = alloc((size_t)BATCH * N_E * 4);   // probe dummy state
    size_t o_di      = alloc((size_t)BATCH * N_E * 4);
    size_t o_dcnt    = alloc((size_t)BATCH * N_E * 4);
    size_t o_iinp    = off;

    int tc = 0;
    if (ws_size > o_iinp) {
        size_t avail = ws_size - o_iinp;
        tc = TSTEPS;
        while (tc >= 2 && (size_t)tc * BATCH * N_TOT * 4 > avail) tc >>= 1;
        if (tc < 2) tc = 0;
    }

    unsigned* p_cnt     = (unsigned*)(ws + o_cnt);
    unsigned* p_colinfo = (unsigned*)(ws + o_colinfo);
    unsigned* p_cursor  = (unsigned*)(ws + o_cursor);
    unsigned* p_nzd     = (unsigned*)(ws + o_nzd);
    float*    p_ve      = (float*)(ws + o_ve);
    float*    p_ie      = (float*)(ws + o_ie);
    float*    p_vi      = (float*)(ws + o_vi);
    float*    p_ii      = (float*)(ws + o_ii);
    unsigned* p_gcnt    = (unsigned*)(ws + o_gcnt);
    int*      p_glist   = (int*)(ws + o_glist);
    int*      p_gnspk   = (int*)(ws + o_gnspk);
    float*    p_dv      = (float*)(ws + o_dv);
    float*    p_di      = (float*)(ws + o_di);
    unsigned* p_dcnt    = (unsigned*)(ws + o_dcnt);
    float*    p_iinp    = (float*)(ws + o_iinp);

    // ---- build CSC of relu'd sparse weights ----
    hipMemsetAsync(ws + o_cnt, 0, (size_t)N_TOT * 4, stream);
    const long total = (long)N_E * N_E + (long)N_I * N_E + (long)N_E * N_I + (long)N_I * N_I;
    int nblk = (int)((total + 255) / 256);
    count_kernel<<<nblk, 256, 0, stream>>>(Wee, Wie, Wei, Wii, p_cnt);
    scan_kernel<<<1, 256, 0, stream>>>(p_cnt, p_colinfo, p_cursor);
    fill_kernel<<<nblk, 256, 0, stream>>>(Wee, Wie, Wei, Wii, p_cursor, p_nzd);

    if (tc >= 2) {
        // chunk 0 projection, then the three measurement probes
        dim3 pg(N_TOT / PBN, (tc * BATCH) / PBM);
        proj_kernel<<<pg, 256, 0, stream>>>(x, We_in, Wi_in, p_iinp, 0);
        sim_probe<0><<<BATCH, 1024, 0, stream>>>(p_iinp, p_colinfo, p_nzd,
                                                 p_dv, p_di, p_dcnt, tc);
        sim_probe<400><<<BATCH, 1024, 0, stream>>>(p_iinp, p_colinfo, p_nzd,
                                                   p_dv, p_di, p_dcnt, tc);
        sim_probe<800><<<BATCH, 1024, 0, stream>>>(p_iinp, p_colinfo, p_nzd,
                                                   p_dv, p_di, p_dcnt, tc);
        // real pipeline
        for (int t0 = 0; t0 < TSTEPS; t0 += tc) {
            if (t0 > 0)
                proj_kernel<<<pg, 256, 0, stream>>>(x, We_in, Wi_in, p_iinp, t0);
            sim_kernel<<<BATCH, 1024, 0, stream>>>(
                p_iinp, x, We_in, Wi_in, p_colinfo, p_nzd,
                p_ve, p_ie, p_vi, p_ii, p_gcnt, p_glist, p_gnspk,
                t0, tc, (t0 == 0) ? 1 : 0);
        }
    } else {
        sim_kernel<<<BATCH, 1024, 0, stream>>>(
            nullptr, x, We_in, Wi_in, p_colinfo, p_nzd,
            p_ve, p_ie, p_vi, p_ii, p_gcnt, p_glist, p_gnspk,
            0, TSTEPS, 1);
    }

    // ---- readout ----
    readout_kernel<<<BATCH, 256, 0, stream>>>(p_gcnt, rw, rb, out);
}

// Round 10
// 3137.950 us; speedup vs baseline: 18.3069x; 18.3069x over previous
//
#include <hip/hip_runtime.h>
#include <hip/hip_fp16.h>
#include <cstdint>
#include <cstddef>

#define N_E 2048
#define N_I 512
#define N_TOT 2560
#define BATCH 64
#define TSTEPS 512
#define INDIM 128

// ------------------------------------------------------------------
// Dense signed-relu weight table Wd[pre][post] (fp16), built by tiled
// transpose from the four row-major [post][pre] matrices.
//   pre<2048,post<2048: +relu(Wee[post][pre])
//   pre<2048,post>=2048: +relu(Wie[post-2048][pre])
//   pre>=2048,post<2048: -relu(Wei[post][pre-2048])
//   pre>=2048,post>=2048: -relu(Wii[post-2048][pre-2048])
// ------------------------------------------------------------------
#define TS 64
__global__ __launch_bounds__(256) void build_wd_kernel(
    const float* __restrict__ Wee, const float* __restrict__ Wie,
    const float* __restrict__ Wei, const float* __restrict__ Wii,
    __half* __restrict__ Wd)
{
    __shared__ float tile[TS][TS + 1];
    int P0 = blockIdx.x * TS;   // pre base
    int Q0 = blockIdx.y * TS;   // post base
    int tx = threadIdx.x & 63, ty = threadIdx.x >> 6;

    const float* W; int ldw, po_off, pr_off; float sign;
    bool preE = (P0 < N_E), postE = (Q0 < N_E);
    if (postE && preE)        { W = Wee; ldw = N_E; po_off = 0;   pr_off = 0;   sign =  1.f; }
    else if (!postE && preE)  { W = Wie; ldw = N_E; po_off = N_E; pr_off = 0;   sign =  1.f; }
    else if (postE && !preE)  { W = Wei; ldw = N_I; po_off = 0;   pr_off = N_E; sign = -1.f; }
    else                      { W = Wii; ldw = N_I; po_off = N_E; pr_off = N_E; sign = -1.f; }

    // read rows=posts, coalesced along pre
    for (int r = ty; r < TS; r += 4) {
        int post = Q0 + r, pre = P0 + tx;
        float v = W[(size_t)(post - po_off) * ldw + (pre - pr_off)];
        tile[r][tx] = (v > 0.f) ? sign * v : 0.f;
    }
    __syncthreads();
    // write rows=pres, coalesced along post: Wd[P0+r][Q0+tx] = tile[tx][r]
    for (int r = ty; r < TS; r += 4) {
        int pre = P0 + r, post = Q0 + tx;
        Wd[(size_t)pre * N_TOT + post] = __float2half(tile[tx][r]);
    }
}

// ------------------------------------------------------------------
// Input projection GEMM: out[(tl*64+b)*2560 + n] = dot(x[b,t0+tl,:], W[n,:])
// ------------------------------------------------------------------
#define PBM 128
#define PBN 64
#define PBK 32
__global__ __launch_bounds__(256) void proj_kernel(
    const float* __restrict__ x, const float* __restrict__ We, const float* __restrict__ Wi,
    float* __restrict__ out, int t0)
{
    __shared__ __align__(16) float As[PBK][132];
    __shared__ __align__(16) float Bs[PBK][68];
    int tid = threadIdx.x;
    int bx = blockIdx.x, by = blockIdx.y;
    int tx = tid & 15, ty = tid >> 4;
    float acc[8][4];
#pragma unroll
    for (int i = 0; i < 8; ++i)
#pragma unroll
        for (int j = 0; j < 4; ++j) acc[i][j] = 0.0f;

    for (int kb = 0; kb < INDIM; kb += PBK) {
#pragma unroll
        for (int it = 0; it < 4; ++it) {
            int idx = it * 256 + tid;
            int kq = idx & 7, ml = idx >> 3;
            int m = by * PBM + ml;
            int b = m & 63, tl = m >> 6;
            const float* arow = x + ((size_t)b * TSTEPS + (size_t)(t0 + tl)) * INDIM;
            float4 v = *(const float4*)(arow + kb + kq * 4);
            As[kq * 4 + 0][ml] = v.x; As[kq * 4 + 1][ml] = v.y;
            As[kq * 4 + 2][ml] = v.z; As[kq * 4 + 3][ml] = v.w;
        }
#pragma unroll
        for (int it = 0; it < 2; ++it) {
            int idx = it * 256 + tid;
            int kq = idx & 7, nl = idx >> 3;
            int n = bx * PBN + nl;
            const float* brow = (n < N_E) ? (We + (size_t)n * INDIM)
                                          : (Wi + (size_t)(n - N_E) * INDIM);
            float4 v = *(const float4*)(brow + kb + kq * 4);
            Bs[kq * 4 + 0][nl] = v.x; Bs[kq * 4 + 1][nl] = v.y;
            Bs[kq * 4 + 2][nl] = v.z; Bs[kq * 4 + 3][nl] = v.w;
        }
        __syncthreads();
#pragma unroll
        for (int k = 0; k < PBK; ++k) {
            float4 a0 = *(const float4*)&As[k][ty * 8];
            float4 a1 = *(const float4*)&As[k][ty * 8 + 4];
            float4 b0 = *(const float4*)&Bs[k][tx * 4];
            float a[8] = {a0.x, a0.y, a0.z, a0.w, a1.x, a1.y, a1.z, a1.w};
            float bb[4] = {b0.x, b0.y, b0.z, b0.w};
#pragma unroll
            for (int i = 0; i < 8; ++i)
#pragma unroll
                for (int j = 0; j < 4; ++j)
                    acc[i][j] = fmaf(a[i], bb[j], acc[i][j]);
        }
        __syncthreads();
    }
#pragma unroll
    for (int i = 0; i < 8; ++i) {
        int m = by * PBM + ty * 8 + i;
        float4 o = make_float4(acc[i][0], acc[i][1], acc[i][2], acc[i][3]);
        *(float4*)(out + (size_t)m * N_TOT + bx * PBN + tx * 4) = o;
    }
}

// ------------------------------------------------------------------
// Persistent per-batch LIF sim — PULL design, no LDS accumulator,
// no atomics on the synaptic path.
//   640 threads/block; thread t owns posts 4t..4t+3 (v,i,cnt,I in regs).
//   Per step: read spike list (ns ~ 6) -> each thread ushort4-loads
//   Wd[j][4t..4t+3] per spike and accumulates -> LIF -> ballot append.
//   LDS: double-buffered spike list only. 2 barriers/step.
// ------------------------------------------------------------------
__global__ __launch_bounds__(640) void sim_kernel(
    const float* __restrict__ i_inp,   // precomputed input currents; may be null
    const float* __restrict__ x, const float* __restrict__ We_in, const float* __restrict__ Wi_in,
    const __half* __restrict__ Wd,
    float* __restrict__ gv, float* __restrict__ gi, unsigned* __restrict__ g_cnt,
    int* __restrict__ g_list, int* __restrict__ g_nspk,
    int t0, int tc, int first)
{
    __shared__ int list_s[2][N_TOT];
    __shared__ int nspk_s[2];

    int b = blockIdx.x, tid = threadIdx.x, lane = tid & 63;
    int p0 = tid * 4;
    bool isE = (tid < 512);            // posts 4t..4t+3 uniformly E or I (2048 % 4 == 0)
    float tm = isE ? 0.05f : 0.1f;

    float v0, v1, v2, v3, c0, c1, c2, c3;
    unsigned n0c = 0u, n1c = 0u, n2c = 0u, n3c = 0u;
    if (first) {
        v0 = v1 = v2 = v3 = 0.f; c0 = c1 = c2 = c3 = 0.f;
        if (tid == 0) nspk_s[0] = 0;
    } else {
        float4 vv = *(const float4*)(gv + (size_t)b * N_TOT + p0);
        float4 cc = *(const float4*)(gi + (size_t)b * N_TOT + p0);
        v0 = vv.x; v1 = vv.y; v2 = vv.z; v3 = vv.w;
        c0 = cc.x; c1 = cc.y; c2 = cc.z; c3 = cc.w;
        if (isE) {
            uint4 q = *(const uint4*)(g_cnt + (size_t)b * N_E + p0);
            n0c = q.x; n1c = q.y; n2c = q.z; n3c = q.w;
        }
        if (tid == 0) nspk_s[0] = g_nspk[b];
    }
    __syncthreads();
    if (!first) {
        int n0 = nspk_s[0];
        for (int s = tid; s < n0; s += 640) list_s[0][s] = g_list[(size_t)b * N_TOT + s];
    }
    __syncthreads();

    const unsigned short* Wdu = (const unsigned short*)Wd;

    for (int tl = 0; tl < tc; ++tl) {
        int cur = tl & 1, nxt = cur ^ 1;
        if (tid == 0) nspk_s[nxt] = 0;

        // input currents for this step (independent load, overlaps gather)
        float I0, I1, I2, I3;
        if (i_inp) {
            float4 vv = *(const float4*)(i_inp + ((size_t)tl * BATCH + b) * N_TOT + p0);
            I0 = vv.x; I1 = vv.y; I2 = vv.z; I3 = vv.w;
        } else {
            const float* xr = x + ((size_t)b * TSTEPS + (size_t)(t0 + tl)) * INDIM;
            const float* w0 = isE ? (We_in + (size_t)p0 * INDIM)
                                  : (Wi_in + (size_t)(p0 - N_E) * INDIM);
            I0 = I1 = I2 = I3 = 0.f;
            for (int k = 0; k < INDIM; ++k) {
                float xv = xr[k];
                I0 = fmaf(w0[k], xv, I0);
                I1 = fmaf(w0[INDIM + k], xv, I1);
                I2 = fmaf(w0[2 * INDIM + k], xv, I2);
                I3 = fmaf(w0[3 * INDIM + k], xv, I3);
            }
        }

        // gather: pull dense fp16 rows of the spiking pre-neurons
        int ns = nspk_s[cur];
        const int* lst = list_s[cur];
        for (int s0 = 0; s0 < ns; s0 += 4) {
            int nl = ns - 1;
            int sB = s0 + 1 < ns ? s0 + 1 : nl;
            int sC = s0 + 2 < ns ? s0 + 2 : nl;
            int sD = s0 + 3 < ns ? s0 + 3 : nl;
            int jA = lst[s0], jB = lst[sB], jC = lst[sC], jD = lst[sD];
            ushort4 wA = *(const ushort4*)(Wdu + (size_t)jA * N_TOT + p0);
            ushort4 wB = *(const ushort4*)(Wdu + (size_t)jB * N_TOT + p0);
            ushort4 wC = *(const ushort4*)(Wdu + (size_t)jC * N_TOT + p0);
            ushort4 wD = *(const ushort4*)(Wdu + (size_t)jD * N_TOT + p0);
            I0 += __half2float(__ushort_as_half(wA.x));
            I1 += __half2float(__ushort_as_half(wA.y));
            I2 += __half2float(__ushort_as_half(wA.z));
            I3 += __half2float(__ushort_as_half(wA.w));
            if (s0 + 1 < ns) {
                I0 += __half2float(__ushort_as_half(wB.x));
                I1 += __half2float(__ushort_as_half(wB.y));
                I2 += __half2float(__ushort_as_half(wB.z));
                I3 += __half2float(__ushort_as_half(wB.w));
            }
            if (s0 + 2 < ns) {
                I0 += __half2float(__ushort_as_half(wC.x));
                I1 += __half2float(__ushort_as_half(wC.y));
                I2 += __half2float(__ushort_as_half(wC.z));
                I3 += __half2float(__ushort_as_half(wC.w));
            }
            if (s0 + 3 < ns) {
                I0 += __half2float(__ushort_as_half(wD.x));
                I1 += __half2float(__ushort_as_half(wD.y));
                I2 += __half2float(__ushort_as_half(wD.z));
                I3 += __half2float(__ushort_as_half(wD.w));
            }
        }

        // LIF in registers
        float vd0 = v0 + tm * (c0 - v0); bool z0 = vd0 > 1.0f; v0 = z0 ? 0.f : vd0; c0 = 0.8f * c0 + I0;
        float vd1 = v1 + tm * (c1 - v1); bool z1 = vd1 > 1.0f; v1 = z1 ? 0.f : vd1; c1 = 0.8f * c1 + I1;
        float vd2 = v2 + tm * (c2 - v2); bool z2 = vd2 > 1.0f; v2 = z2 ? 0.f : vd2; c2 = 0.8f * c2 + I2;
        float vd3 = v3 + tm * (c3 - v3); bool z3 = vd3 > 1.0f; v3 = z3 ? 0.f : vd3; c3 = 0.8f * c3 + I3;
        if (isE) { n0c += z0; n1c += z1; n2c += z2; n3c += z3; }

        __syncthreads();   // barrier 1: all reads of cur-slot done; reset visible

        // aggregated spike append (one LDS atomic per wave)
        unsigned long long m0 = __ballot(z0), m1 = __ballot(z1);
        unsigned long long m2 = __ballot(z2), m3 = __ballot(z3);
        int w0c = __popcll(m0), w1c = __popcll(m1), w2c = __popcll(m2), w3c = __popcll(m3);
        int tot = w0c + w1c + w2c + w3c;
        if (tot) {
            int base = 0;
            if (lane == 0) base = atomicAdd(&nspk_s[nxt], tot);
            base = __shfl(base, 0);
            unsigned long long pre = (1ull << lane) - 1ull;
            if (z0) list_s[nxt][base + __popcll(m0 & pre)] = p0;
            if (z1) list_s[nxt][base + w0c + __popcll(m1 & pre)] = p0 + 1;
            if (z2) list_s[nxt][base + w0c + w1c + __popcll(m2 & pre)] = p0 + 2;
            if (z3) list_s[nxt][base + w0c + w1c + w2c + __popcll(m3 & pre)] = p0 + 3;
        }
        __syncthreads();   // barrier 2: appends complete
    }

    // persist state
    *(float4*)(gv + (size_t)b * N_TOT + p0) = make_float4(v0, v1, v2, v3);
    *(float4*)(gi + (size_t)b * N_TOT + p0) = make_float4(c0, c1, c2, c3);
    if (isE) *(uint4*)(g_cnt + (size_t)b * N_E + p0) = make_uint4(n0c, n1c, n2c, n3c);
    int fin = tc & 1;
    if (tid == 0) g_nspk[b] = nspk_s[fin];
    for (int s = tid; s < nspk_s[fin]; s += 640) g_list[(size_t)b * N_TOT + s] = list_s[fin][s];
}

// ------------------------------------------------------------------
// Readout: out[b, o] = (1/512) * sum_n cnt[b,n] * rw[o,n] + rb[o]
// ------------------------------------------------------------------
__global__ __launch_bounds__(256) void readout_kernel(
    const unsigned* __restrict__ g_cnt,
    const float* __restrict__ rw, const float* __restrict__ rb, float* __restrict__ out)
{
    int b = blockIdx.x, tid = threadIdx.x;
    float a0 = 0.f, a1 = 0.f, a2 = 0.f;
    for (int n = tid; n < N_E; n += 256) {
        float c = (float)g_cnt[(size_t)b * N_E + n];
        a0 = fmaf(c, rw[n], a0);
        a1 = fmaf(c, rw[N_E + n], a1);
        a2 = fmaf(c, rw[2 * N_E + n], a2);
    }
#pragma unroll
    for (int off = 32; off > 0; off >>= 1) {
        a0 += __shfl_down(a0, off);
        a1 += __shfl_down(a1, off);
        a2 += __shfl_down(a2, off);
    }
    __shared__ float part[3][4];
    int wid = tid >> 6, lane = tid & 63;
    if (lane == 0) { part[0][wid] = a0; part[1][wid] = a1; part[2][wid] = a2; }
    __syncthreads();
    if (tid == 0) {
        float s0 = part[0][0] + part[0][1] + part[0][2] + part[0][3];
        float s1 = part[1][0] + part[1][1] + part[1][2] + part[1][3];
        float s2 = part[2][0] + part[2][1] + part[2][2] + part[2][3];
        const float inv = 1.0f / 512.0f;
        out[b * 3 + 0] = fmaf(s0, inv, rb[0]);
        out[b * 3 + 1] = fmaf(s1, inv, rb[1]);
        out[b * 3 + 2] = fmaf(s2, inv, rb[2]);
    }
}

// ------------------------------------------------------------------
extern "C" void kernel_launch(void* const* d_in, const int* in_sizes, int n_in,
                              void* d_out, int out_size, void* d_ws, size_t ws_size,
                              hipStream_t stream)
{
    const float* x     = (const float*)d_in[0];
    const float* Wee   = (const float*)d_in[1];
    const float* Wie   = (const float*)d_in[2];
    const float* Wei   = (const float*)d_in[3];
    const float* Wii   = (const float*)d_in[4];
    const float* We_in = (const float*)d_in[5];
    const float* Wi_in = (const float*)d_in[6];
    const float* rw    = (const float*)d_in[7];
    const float* rb    = (const float*)d_in[8];
    float* out = (float*)d_out;
    char* ws = (char*)d_ws;

    size_t off = 0;
    auto alloc = [&](size_t bytes) {
        size_t o = off;
        off = (off + bytes + 255) & ~(size_t)255;
        return o;
    };
    size_t o_wd    = alloc((size_t)N_TOT * N_TOT * 2);        // 13.1 MB dense fp16
    size_t o_gv    = alloc((size_t)BATCH * N_TOT * 4);
    size_t o_gi    = alloc((size_t)BATCH * N_TOT * 4);
    size_t o_gcnt  = alloc((size_t)BATCH * N_E * 4);
    size_t o_glist = alloc((size_t)BATCH * N_TOT * 4);
    size_t o_gnspk = alloc((size_t)BATCH * 4);
    size_t o_iinp  = off;   // remainder for the input-projection chunk

    int tc = 0;
    if (ws_size > o_iinp) {
        size_t avail = ws_size - o_iinp;
        tc = TSTEPS;
        while (tc >= 2 && (size_t)tc * BATCH * N_TOT * 4 > avail) tc >>= 1;
        if (tc < 2) tc = 0;
    }

    __half*   p_wd    = (__half*)(ws + o_wd);
    float*    p_gv    = (float*)(ws + o_gv);
    float*    p_gi    = (float*)(ws + o_gi);
    unsigned* p_gcnt  = (unsigned*)(ws + o_gcnt);
    int*      p_glist = (int*)(ws + o_glist);
    int*      p_gnspk = (int*)(ws + o_gnspk);
    float*    p_iinp  = (float*)(ws + o_iinp);

    // ---- build dense signed-relu fp16 table ----
    dim3 wg(N_TOT / TS, N_TOT / TS);
    build_wd_kernel<<<wg, 256, 0, stream>>>(Wee, Wie, Wei, Wii, p_wd);

    // ---- time loop: proj GEMM chunk + persistent sim ----
    if (tc >= 2) {
        for (int t0 = 0; t0 < TSTEPS; t0 += tc) {
            dim3 pg(N_TOT / PBN, (tc * BATCH) / PBM);
            proj_kernel<<<pg, 256, 0, stream>>>(x, We_in, Wi_in, p_iinp, t0);
            sim_kernel<<<BATCH, 640, 0, stream>>>(
                p_iinp, x, We_in, Wi_in, p_wd,
                p_gv, p_gi, p_gcnt, p_glist, p_gnspk,
                t0, tc, (t0 == 0) ? 1 : 0);
        }
    } else {
        sim_kernel<<<BATCH, 640, 0, stream>>>(
            nullptr, x, We_in, Wi_in, p_wd,
            p_gv, p_gi, p_gcnt, p_glist, p_gnspk,
            0, TSTEPS, 1);
    }

    // ---- readout ----
    readout_kernel<<<BATCH, 256, 0, stream>>>(p_gcnt, rw, rb, out);
}